// Round 14
// baseline (1030.254 us; speedup 1.0000x reference)
//
#include <hip/hip_runtime.h>

#define HID 3072
#define LSEQ 2048
#define NH 24
#define HD 128
#define N1 21504   // 3*HID + MLP
#define K2 15360   // HID + MLP

typedef unsigned short ushort_t;
typedef __attribute__((ext_vector_type(8))) short bf16x8;
typedef __attribute__((ext_vector_type(4))) float f32x4;

__device__ __forceinline__ unsigned short f2bf(float f) {
    union { float f; unsigned int u; } v; v.f = f;
    unsigned int u = v.u;
    u += 0x7fffu + ((u >> 16) & 1u);   // RNE
    return (unsigned short)(u >> 16);
}
__device__ __forceinline__ float bf2f(unsigned short s) {
    union { unsigned int u; float f; } v; v.u = ((unsigned int)s) << 16;
    return v.f;
}
__device__ __forceinline__ float gelu_tanh(float x) {
    float u = 0.7978845608028654f * (x + 0.044715f * x * x * x);
    float t = 2.0f / (1.0f + __expf(-2.0f * u)) - 1.0f;
    return 0.5f * x * (1.0f + t);
}
__device__ __forceinline__ void gload_lds16(const ushort_t* g, ushort_t* l) {
    __builtin_amdgcn_global_load_lds((const __attribute__((address_space(1))) void*)g,
                                     (__attribute__((address_space(3))) void*)l, 16, 0, 0);
}

// ---------------- f32 -> bf16 conversion of both weight matrices, one launch ----------------
__global__ __launch_bounds__(256) void k_cvt2(const float* __restrict__ s1,
    ushort_t* __restrict__ d1, int n1, const float* __restrict__ s2,
    ushort_t* __restrict__ d2, int n2)
{
    int stride = gridDim.x * 256 * 8;
    int base = (blockIdx.x * 256 + threadIdx.x) * 8;
    for (int i = base; i < n1; i += stride) {
        float4 a = *reinterpret_cast<const float4*>(s1 + i);
        float4 b = *reinterpret_cast<const float4*>(s1 + i + 4);
        uint4 pk;
        pk.x = (unsigned)f2bf(a.x) | ((unsigned)f2bf(a.y) << 16);
        pk.y = (unsigned)f2bf(a.z) | ((unsigned)f2bf(a.w) << 16);
        pk.z = (unsigned)f2bf(b.x) | ((unsigned)f2bf(b.y) << 16);
        pk.w = (unsigned)f2bf(b.z) | ((unsigned)f2bf(b.w) << 16);
        *reinterpret_cast<uint4*>(d1 + i) = pk;
    }
    for (int i = base; i < n2; i += stride) {
        float4 a = *reinterpret_cast<const float4*>(s2 + i);
        float4 b = *reinterpret_cast<const float4*>(s2 + i + 4);
        uint4 pk;
        pk.x = (unsigned)f2bf(a.x) | ((unsigned)f2bf(a.y) << 16);
        pk.y = (unsigned)f2bf(a.z) | ((unsigned)f2bf(a.w) << 16);
        pk.z = (unsigned)f2bf(b.x) | ((unsigned)f2bf(b.y) << 16);
        pk.w = (unsigned)f2bf(b.z) | ((unsigned)f2bf(b.w) << 16);
        *reinterpret_cast<uint4*>(d2 + i) = pk;
    }
}

// ---------------- mod = silu(vec) @ mod_w.T + mod_b ----------------
__global__ __launch_bounds__(256) void k_mod(const float* __restrict__ vec,
    const float* __restrict__ mw, const float* __restrict__ mb, float* __restrict__ mod) {
    __shared__ __align__(16) float sv[HID];
    int tid = threadIdx.x;
    for (int i = tid; i < HID; i += 256) {
        float v = vec[i];
        sv[i] = v / (1.0f + __expf(-v));
    }
    __syncthreads();
    int wave = tid >> 6, lane = tid & 63;
    int n = blockIdx.x * 4 + wave;
    const float* w = mw + (size_t)n * HID;
    float acc = 0.0f;
    for (int k = lane * 4; k < HID; k += 256) {
        float4 wv = *reinterpret_cast<const float4*>(w + k);
        float4 s  = *reinterpret_cast<const float4*>(sv + k);
        acc += wv.x * s.x + wv.y * s.y + wv.z * s.z + wv.w * s.w;
    }
    #pragma unroll
    for (int off = 1; off < 64; off <<= 1) acc += __shfl_xor(acc, off);
    if (lane == 0) mod[n] = acc + mb[n];
}

// ---------------- LayerNorm + (1+scale)*ln + shift -> bf16 ----------------
__global__ __launch_bounds__(256) void k_lnmod(const float* __restrict__ x,
    const float* __restrict__ mod, ushort_t* __restrict__ xmod) {
    int row = blockIdx.x, tid = threadIdx.x;
    const float4* xr = reinterpret_cast<const float4*>(x + (size_t)row * HID);
    float4 v[3];
    float s = 0.f, sq = 0.f;
    #pragma unroll
    for (int i = 0; i < 3; ++i) {
        v[i] = xr[tid + i * 256];
        s  += v[i].x + v[i].y + v[i].z + v[i].w;
        sq += v[i].x * v[i].x + v[i].y * v[i].y + v[i].z * v[i].z + v[i].w * v[i].w;
    }
    #pragma unroll
    for (int off = 1; off < 64; off <<= 1) { s += __shfl_xor(s, off); sq += __shfl_xor(sq, off); }
    __shared__ float rs[4], rq[4];
    int wave = tid >> 6, lane = tid & 63;
    if (lane == 0) { rs[wave] = s; rq[wave] = sq; }
    __syncthreads();
    s  = rs[0] + rs[1] + rs[2] + rs[3];
    sq = rq[0] + rq[1] + rq[2] + rq[3];
    float mean = s * (1.0f / HID);
    float var = sq * (1.0f / HID) - mean * mean;
    float rstd = rsqrtf(var + 1e-6f);
    ushort_t* orow = xmod + (size_t)row * HID;
    #pragma unroll
    for (int i = 0; i < 3; ++i) {
        int c = (tid + i * 256) * 4;
        float4 sc = *reinterpret_cast<const float4*>(mod + HID + c);
        float4 sh = *reinterpret_cast<const float4*>(mod + c);
        float o0 = (1.f + sc.x) * ((v[i].x - mean) * rstd) + sh.x;
        float o1 = (1.f + sc.y) * ((v[i].y - mean) * rstd) + sh.y;
        float o2 = (1.f + sc.z) * ((v[i].z - mean) * rstd) + sh.z;
        float o3 = (1.f + sc.w) * ((v[i].w - mean) * rstd) + sh.w;
        *reinterpret_cast<ushort4*>(orow + c) = make_ushort4(f2bf(o0), f2bf(o1), f2bf(o2), f2bf(o3));
    }
}

#define MFMA_CLUSTER(PH, AF)                                                          \
    do {                                                                              \
        __builtin_amdgcn_s_setprio(1);                                                \
        _Pragma("unroll") for (int i_ = 0; i_ < 2; ++i_)                              \
        _Pragma("unroll") for (int nj_ = 0; nj_ < 4; ++nj_)                           \
        _Pragma("unroll") for (int kh_ = 0; kh_ < 2; ++kh_)                           \
            acc[2 * (PH) + i_][nj_] = __builtin_amdgcn_mfma_f32_16x16x32_bf16(        \
                AF[i_][kh_], bfrag[nj_][kh_], acc[2 * (PH) + i_][nj_], 0, 0, 0);      \
        __builtin_amdgcn_s_setprio(0);                                                \
    } while (0)

// ---------------- GEMM1: 256x256, BK=64, 8 waves, 160KB LDS (best-measured) ----------------
__global__ __launch_bounds__(512) void k_gemm8(
    const ushort_t* __restrict__ A, const ushort_t* __restrict__ W,
    const float* __restrict__ bias,
    ushort_t* __restrict__ out_qkv, ushort_t* __restrict__ out_concat)
{
    extern __shared__ __align__(16) char smem_raw[];
    ushort_t* smem = (ushort_t*)smem_raw;   // [A0|A1|A2: 3*16384][B0|B1: 2*16384] elements
    const int Ks = HID;
    int tid = threadIdx.x;
    int wid = tid >> 6, l = tid & 63;
    int wm = wid >> 2, wn = wid & 3;
    int lr = l & 15, lg = l >> 4;

    int flat = blockIdx.y * 84 + blockIdx.x;
    int nf = (flat & 7) * 84 + (flat >> 3);
    int mt = nf & 7, nt = nf >> 3;
    int m0 = mt * 256, n0 = nt * 256;
    int NT = Ks >> 6;

    int lrow = l >> 3;
    int lc   = (l & 7) ^ lrow;       // pre-swizzled source chunk
    int arow_st = wm * 128 + wn * 32 + lrow;
    int bhalf = wn >> 1, ridx = wm * 2 + (wn & 1);
    int brow_st = bhalf * 128 + ridx * 32 + lrow;
    const ushort_t* aSrc = A + (size_t)(m0 + arow_st) * Ks + lc * 8;
    const ushort_t* bSrc = W + (size_t)(n0 + brow_st) * Ks + lc * 8;
    int aDst = (wm * 128 + wn * 32) * 64;
    int bDst = (bhalf * 128 + ridx * 32) * 64;

    auto stageA = [&](int t, int buf, int c) {
        gload_lds16(aSrc + (size_t)c * 8 * Ks + (size_t)t * 64,
                    smem + buf * 16384 + aDst + c * 512);
    };
    auto stageB = [&](int t, int c) {
        gload_lds16(bSrc + (size_t)c * 8 * Ks + (size_t)t * 64,
                    smem + 49152 + (t & 1) * 16384 + bDst + c * 512);
    };
    auto readA = [&](int buf, int row, int ccc) {
        return *reinterpret_cast<const bf16x8*>(smem + buf * 16384 + row * 64 + ((ccc ^ (row & 7)) << 3));
    };
    auto readB = [&](int p, int row, int ccc) {
        return *reinterpret_cast<const bf16x8*>(smem + 49152 + p * 16384 + row * 64 + ((ccc ^ (row & 7)) << 3));
    };

    f32x4 acc[8][4] = {};

    #pragma unroll
    for (int c = 0; c < 4; ++c) stageA(0, 0, c);
    #pragma unroll
    for (int c = 0; c < 4; ++c) stageB(0, c);
    #pragma unroll
    for (int c = 0; c < 4; ++c) stageA(1, 1, c);
    #pragma unroll
    for (int c = 0; c < 4; ++c) stageB(1, c);
    asm volatile("s_waitcnt vmcnt(8)" ::: "memory");
    __builtin_amdgcn_s_barrier();

    int pA = 0, pA2 = 2;
    for (int t = 0; t < NT; ++t) {
        int pB = t & 1;
        bf16x8 bfrag[4][2], af0[2][2], af1[2][2], af2[2][2], af3[2][2];
        #pragma unroll
        for (int nj = 0; nj < 4; ++nj)
            #pragma unroll
            for (int kh = 0; kh < 2; ++kh)
                bfrag[nj][kh] = readB(pB, wn * 64 + nj * 16 + lr, kh * 4 + lg);
        #pragma unroll
        for (int i = 0; i < 2; ++i)
            #pragma unroll
            for (int kh = 0; kh < 2; ++kh)
                af0[i][kh] = readA(pA, wm * 128 + i * 16 + lr, kh * 4 + lg);
        if (t + 2 < NT) {
            stageA(t + 2, pA2, 0); stageA(t + 2, pA2, 1);
            stageA(t + 2, pA2, 2); stageA(t + 2, pA2, 3);
        }
        #pragma unroll
        for (int i = 0; i < 2; ++i)
            #pragma unroll
            for (int kh = 0; kh < 2; ++kh)
                af1[i][kh] = readA(pA, wm * 128 + (2 + i) * 16 + lr, kh * 4 + lg);
        MFMA_CLUSTER(0, af0);
        #pragma unroll
        for (int i = 0; i < 2; ++i)
            #pragma unroll
            for (int kh = 0; kh < 2; ++kh)
                af2[i][kh] = readA(pA, wm * 128 + (4 + i) * 16 + lr, kh * 4 + lg);
        MFMA_CLUSTER(1, af1);
        __builtin_amdgcn_s_barrier();   // all waves consumed B(t)
        if (t + 2 < NT) {
            stageB(t + 2, 0); stageB(t + 2, 1);
            stageB(t + 2, 2); stageB(t + 2, 3);
        }
        #pragma unroll
        for (int i = 0; i < 2; ++i)
            #pragma unroll
            for (int kh = 0; kh < 2; ++kh)
                af3[i][kh] = readA(pA, wm * 128 + (6 + i) * 16 + lr, kh * 4 + lg);
        MFMA_CLUSTER(2, af2);
        MFMA_CLUSTER(3, af3);
        if (t + 2 < NT)      asm volatile("s_waitcnt vmcnt(8)" ::: "memory");
        else if (t + 1 < NT) asm volatile("s_waitcnt vmcnt(0)" ::: "memory");
        __builtin_amdgcn_s_barrier();
        pA  = (pA  + 1 == 3) ? 0 : pA  + 1;
        pA2 = (pA2 + 1 == 3) ? 0 : pA2 + 1;
    }

    #pragma unroll
    for (int nj = 0; nj < 4; ++nj) {
        int col = n0 + wn * 64 + nj * 16 + lr;
        float b = bias[col];
        #pragma unroll
        for (int mi = 0; mi < 8; ++mi) {
            int rbase = m0 + wm * 128 + mi * 16 + lg * 4;
            #pragma unroll
            for (int r = 0; r < 4; ++r) {
                int mrow = rbase + r;
                float val = acc[mi][nj][r] + b;
                if (col < 3 * HID) {
                    out_qkv[(size_t)mrow * (3 * HID) + col] = f2bf(val);
                } else {
                    out_concat[(size_t)mrow * K2 + HID + (col - 3 * HID)] = f2bf(gelu_tanh(val));
                }
            }
        }
    }
}

#define MFMA_CL4(PH, AF)                                                              \
    do {                                                                              \
        __builtin_amdgcn_s_setprio(1);                                                \
        _Pragma("unroll") for (int nj_ = 0; nj_ < 4; ++nj_)                           \
        _Pragma("unroll") for (int kh_ = 0; kh_ < 2; ++kh_)                           \
            acc[(PH)][nj_] = __builtin_amdgcn_mfma_f32_16x16x32_bf16(                 \
                AF[kh_], bfrag[nj_][kh_], acc[(PH)][nj_], 0, 0, 0);                   \
        __builtin_amdgcn_s_setprio(0);                                                \
    } while (0)

// ---------------- GEMM2: 128x128, BK=64, 4 waves, 80KB LDS, split-K(4), bf16 partials ----------------
__global__ __launch_bounds__(256) void k_gemm4(
    const ushort_t* __restrict__ A, const ushort_t* __restrict__ W,
    int klen, ushort_t* __restrict__ part)
{
    extern __shared__ __align__(16) char smem_raw[];
    ushort_t* smem = (ushort_t*)smem_raw;   // [A0|A1|A2: 3x8192][B0|B1: 2x8192] = 80 KB
    const int Ks = K2;
    int tid = threadIdx.x;
    int wave = tid >> 6, l = tid & 63;
    int wm = wave >> 1, wn = wave & 1;
    int lr = l & 15, lg = l >> 4;

    int flat = blockIdx.y * 24 + blockIdx.x;
    int nf = (flat & 7) * 48 + (flat >> 3);
    int mt = nf & 15, nt = nf >> 4;
    int m0 = mt * 128, n0 = nt * 128;
    int koff = blockIdx.z * klen;
    int NT = klen >> 6;

    int lrow = l >> 3;
    int lc   = (l & 7) ^ lrow;
    const ushort_t* aSrc = A + (size_t)(m0 + wave * 32 + lrow) * Ks + koff + lc * 8;
    const ushort_t* bSrc = W + (size_t)(n0 + wave * 32 + lrow) * Ks + koff + lc * 8;
    int dstBase = wave * 2048;

    auto stageA = [&](int t, int buf) {
        #pragma unroll
        for (int c = 0; c < 4; ++c)
            gload_lds16(aSrc + (size_t)c * 8 * Ks + (size_t)t * 64,
                        smem + buf * 8192 + dstBase + c * 512);
    };
    auto stageB = [&](int t) {
        #pragma unroll
        for (int c = 0; c < 4; ++c)
            gload_lds16(bSrc + (size_t)c * 8 * Ks + (size_t)t * 64,
                        smem + 24576 + (t & 1) * 8192 + dstBase + c * 512);
    };
    auto readA = [&](int buf, int row, int ccc) {
        return *reinterpret_cast<const bf16x8*>(smem + buf * 8192 + row * 64 + ((ccc ^ (row & 7)) << 3));
    };
    auto readB = [&](int p, int row, int ccc) {
        return *reinterpret_cast<const bf16x8*>(smem + 24576 + p * 8192 + row * 64 + ((ccc ^ (row & 7)) << 3));
    };

    f32x4 acc[4][4] = {};

    stageA(0, 0); stageB(0); stageA(1, 1); stageB(1);
    asm volatile("s_waitcnt vmcnt(8)" ::: "memory");
    __builtin_amdgcn_s_barrier();

    int pA = 0, pA2 = 2;
    for (int t = 0; t < NT; ++t) {
        int pB = t & 1;
        bf16x8 bfrag[4][2], af0[2], af1[2], af2[2], af3[2];
        #pragma unroll
        for (int nj = 0; nj < 4; ++nj)
            #pragma unroll
            for (int kh = 0; kh < 2; ++kh)
                bfrag[nj][kh] = readB(pB, wn * 64 + nj * 16 + lr, kh * 4 + lg);
        #pragma unroll
        for (int kh = 0; kh < 2; ++kh)
            af0[kh] = readA(pA, wm * 64 + lr, kh * 4 + lg);
        if (t + 2 < NT) stageA(t + 2, pA2);
        #pragma unroll
        for (int kh = 0; kh < 2; ++kh)
            af1[kh] = readA(pA, wm * 64 + 16 + lr, kh * 4 + lg);
        MFMA_CL4(0, af0);
        #pragma unroll
        for (int kh = 0; kh < 2; ++kh)
            af2[kh] = readA(pA, wm * 64 + 32 + lr, kh * 4 + lg);
        MFMA_CL4(1, af1);
        __builtin_amdgcn_s_barrier();
        if (t + 2 < NT) stageB(t + 2);
        #pragma unroll
        for (int kh = 0; kh < 2; ++kh)
            af3[kh] = readA(pA, wm * 64 + 48 + lr, kh * 4 + lg);
        MFMA_CL4(2, af2);
        MFMA_CL4(3, af3);
        if (t + 2 < NT)      asm volatile("s_waitcnt vmcnt(8)" ::: "memory");
        else if (t + 1 < NT) asm volatile("s_waitcnt vmcnt(0)" ::: "memory");
        __builtin_amdgcn_s_barrier();
        pA  = (pA  + 1 == 3) ? 0 : pA  + 1;
        pA2 = (pA2 + 1 == 3) ? 0 : pA2 + 1;
    }

    #pragma unroll
    for (int nj = 0; nj < 4; ++nj) {
        int col = n0 + wn * 64 + nj * 16 + lr;
        #pragma unroll
        for (int mi = 0; mi < 4; ++mi) {
            int rbase = m0 + wm * 64 + mi * 16 + lg * 4;
            #pragma unroll
            for (int r = 0; r < 4; ++r) {
                int mrow = rbase + r;
                part[(size_t)blockIdx.z * LSEQ * HID + (size_t)mrow * HID + col] = f2bf(acc[mi][nj][r]);
            }
        }
    }
}

// ---------------- split-K(4) bf16 reduce + bias + gate + residual ----------------
__global__ __launch_bounds__(256) void k_red(const ushort_t* __restrict__ part,
    const float* __restrict__ bias, const float* __restrict__ xres,
    const float* __restrict__ mod, float* __restrict__ dout)
{
    size_t base = ((size_t)blockIdx.x * 256 + threadIdx.x) * 8;
    int col = (int)(base % HID);
    float s[8] = {0.f, 0.f, 0.f, 0.f, 0.f, 0.f, 0.f, 0.f};
    #pragma unroll
    for (int z = 0; z < 4; ++z) {
        uint4 pv = *reinterpret_cast<const uint4*>(part + (size_t)z * LSEQ * HID + base);
        unsigned w0 = pv.x, w1 = pv.y, w2 = pv.z, w3 = pv.w;
        s[0] += bf2f((ushort_t)(w0 & 0xffffu)); s[1] += bf2f((ushort_t)(w0 >> 16));
        s[2] += bf2f((ushort_t)(w1 & 0xffffu)); s[3] += bf2f((ushort_t)(w1 >> 16));
        s[4] += bf2f((ushort_t)(w2 & 0xffffu)); s[5] += bf2f((ushort_t)(w2 >> 16));
        s[6] += bf2f((ushort_t)(w3 & 0xffffu)); s[7] += bf2f((ushort_t)(w3 >> 16));
    }
    float4 bb0 = *reinterpret_cast<const float4*>(bias + col);
    float4 bb1 = *reinterpret_cast<const float4*>(bias + col + 4);
    float4 gg0 = *reinterpret_cast<const float4*>(mod + 2 * HID + col);
    float4 gg1 = *reinterpret_cast<const float4*>(mod + 2 * HID + col + 4);
    float4 xx0 = *reinterpret_cast<const float4*>(xres + base);
    float4 xx1 = *reinterpret_cast<const float4*>(xres + base + 4);
    float4 o0, o1;
    o0.x = xx0.x + gg0.x * (s[0] + bb0.x);
    o0.y = xx0.y + gg0.y * (s[1] + bb0.y);
    o0.z = xx0.z + gg0.z * (s[2] + bb0.z);
    o0.w = xx0.w + gg0.w * (s[3] + bb0.w);
    o1.x = xx1.x + gg1.x * (s[4] + bb1.x);
    o1.y = xx1.y + gg1.y * (s[5] + bb1.y);
    o1.z = xx1.z + gg1.z * (s[6] + bb1.z);
    o1.w = xx1.w + gg1.w * (s[7] + bb1.w);
    *reinterpret_cast<float4*>(dout + base) = o0;
    *reinterpret_cast<float4*>(dout + base + 4) = o1;
}

// ---------------- per-(h,l): RMS(q,k) + RoPE, write q_rope/k_rope/q_rms bf16 + V^T ----------------
__global__ __launch_bounds__(256) void k_qkv(const ushort_t* __restrict__ qkv,
    const float* __restrict__ pe, const float* __restrict__ q_scale, const float* __restrict__ k_scale,
    ushort_t* __restrict__ q_rope, ushort_t* __restrict__ k_rope,
    ushort_t* __restrict__ q_rms, ushort_t* __restrict__ v_t)
{
    __shared__ ushort_t vtile[64][132];
    int h = blockIdx.y, l0 = blockIdx.x * 64;
    int wave = threadIdx.x >> 6, lane = threadIdx.x & 63;
    int d0 = lane * 2;
    float qs0 = q_scale[d0], qs1 = q_scale[d0 + 1];
    float ks0 = k_scale[d0], ks1 = k_scale[d0 + 1];
    for (int it = 0; it < 16; ++it) {
        int ll = it * 4 + wave;
        int l = l0 + ll;
        const ushort_t* base = qkv + (size_t)l * (3 * HID) + h * HD + d0;
        unsigned qw = *reinterpret_cast<const unsigned*>(base);
        unsigned kw = *reinterpret_cast<const unsigned*>(base + HID);
        unsigned vw = *reinterpret_cast<const unsigned*>(base + 2 * HID);
        float qx = bf2f((ushort_t)(qw & 0xffffu)), qy = bf2f((ushort_t)(qw >> 16));
        float kx = bf2f((ushort_t)(kw & 0xffffu)), ky = bf2f((ushort_t)(kw >> 16));
        float sq = qx * qx + qy * qy;
        float sk = kx * kx + ky * ky;
        #pragma unroll
        for (int off = 1; off < 64; off <<= 1) { sq += __shfl_xor(sq, off); sk += __shfl_xor(sk, off); }
        float rqv = rsqrtf(sq * (1.0f / HD) + 1e-6f);
        float rkv = rsqrtf(sk * (1.0f / HD) + 1e-6f);
        float qnx = qx * rqv * qs0, qny = qy * rqv * qs1;
        float knx = kx * rkv * ks0, kny = ky * rkv * ks1;
        float4 p = *reinterpret_cast<const float4*>(pe + ((size_t)l * 64 + lane) * 4);
        size_t off_hl = ((size_t)h * LSEQ + l) * HD + d0;
        *reinterpret_cast<unsigned*>(q_rms + off_hl) = (unsigned)f2bf(qnx) | ((unsigned)f2bf(qny) << 16);
        float qrx = p.x * qnx + p.y * qny, qry = p.z * qnx + p.w * qny;
        float krx = p.x * knx + p.y * kny, kry = p.z * knx + p.w * kny;
        *reinterpret_cast<unsigned*>(q_rope + off_hl) = (unsigned)f2bf(qrx) | ((unsigned)f2bf(qry) << 16);
        *reinterpret_cast<unsigned*>(k_rope + off_hl) = (unsigned)f2bf(krx) | ((unsigned)f2bf(kry) << 16);
        vtile[ll][d0] = (ushort_t)(vw & 0xffffu);
        vtile[ll][d0 + 1] = (ushort_t)(vw >> 16);
    }
    __syncthreads();
    int d = threadIdx.x >> 1, half = threadIdx.x & 1;
    ushort_t* dst = v_t + ((size_t)h * HD + d) * LSEQ + l0 + half * 32;
    #pragma unroll
    for (int g = 0; g < 4; ++g) {
        unsigned w0, w1, w2, w3;
        int lb = half * 32 + g * 8;
        w0 = (unsigned)vtile[lb + 0][d] | ((unsigned)vtile[lb + 1][d] << 16);
        w1 = (unsigned)vtile[lb + 2][d] | ((unsigned)vtile[lb + 3][d] << 16);
        w2 = (unsigned)vtile[lb + 4][d] | ((unsigned)vtile[lb + 5][d] << 16);
        w3 = (unsigned)vtile[lb + 6][d] | ((unsigned)vtile[lb + 7][d] << 16);
        reinterpret_cast<uint4*>(dst)[g] = make_uint4(w0, w1, w2, w3);
    }
}

// ---------------- ip k/v projections ----------------
__global__ __launch_bounds__(256) void k_ipgemv(const float* __restrict__ emb,
    const float* __restrict__ wk, const float* __restrict__ wv,
    float* __restrict__ ipk, float* __restrict__ ipv)
{
    int task = blockIdx.x * 4 + (threadIdx.x >> 6);
    int lane = threadIdx.x & 63;
    int which = task / HID;
    int n = task % HID;
    const float* w = (which ? wv : wk) + (size_t)n * HID;
    float acc[16];
    #pragma unroll
    for (int t = 0; t < 16; ++t) acc[t] = 0.f;
    for (int k = lane; k < HID; k += 64) {
        float wval = w[k];
        #pragma unroll
        for (int t = 0; t < 16; ++t) acc[t] += emb[t * HID + k] * wval;
    }
    #pragma unroll
    for (int off = 1; off < 64; off <<= 1) {
        #pragma unroll
        for (int t = 0; t < 16; ++t) acc[t] += __shfl_xor(acc[t], off);
    }
    if (lane == 0) {
        int hh = n >> 7, d = n & 127;
        float* dstp = which ? ipv : ipk;
        #pragma unroll
        for (int t = 0; t < 16; ++t) dstp[((size_t)hh * 16 + t) * HD + d] = acc[t];
    }
}

__global__ __launch_bounds__(256) void k_ipkrms(float* __restrict__ ipk) {
    int row = blockIdx.x * 4 + (threadIdx.x >> 6);
    int lane = threadIdx.x & 63;
    float2 v = *reinterpret_cast<const float2*>(ipk + (size_t)row * HD + lane * 2);
    float sq = v.x * v.x + v.y * v.y;
    #pragma unroll
    for (int off = 1; off < 64; off <<= 1) sq += __shfl_xor(sq, off);
    float r = rsqrtf(sq * (1.0f / HD) + 1e-5f);
    float2 o; o.x = v.x * r; o.y = v.y * r;
    *reinterpret_cast<float2*>(ipk + (size_t)row * HD + lane * 2) = o;
}

// ---------------- flash attention QBLK=64 KVBLK=64 + fused ip-attention epilogue -> concat ----------------
__global__ __launch_bounds__(256) void k_attn(const ushort_t* __restrict__ q_rope,
    const ushort_t* __restrict__ k_rope, const ushort_t* __restrict__ v_t,
    const ushort_t* __restrict__ q_rms, const float* __restrict__ ipk,
    const float* __restrict__ ipv, const float* __restrict__ img_mask,
    ushort_t* __restrict__ concat)
{
    __shared__ __align__(16) ushort_t Ks[64 * 128];    // 16 KB
    __shared__ __align__(16) ushort_t Vs[128 * 64];    // 16 KB
    __shared__ __align__(16) ushort_t Ps[4 * 16 * 72]; // 9 KB  -> 41 KB total, 3 blocks/CU
    const float SC = 0.08838834764831845f;
    int h = blockIdx.y, q0 = blockIdx.x * 64;
    int tid = threadIdx.x, wave = tid >> 6, lane = tid & 63;
    int lr = lane & 15, lg = lane >> 4;
    const ushort_t* Kb = k_rope + (size_t)h * LSEQ * HD;
    const ushort_t* Vb = v_t + (size_t)h * HD * LSEQ;
    bf16x8 qf[4];
    #pragma unroll
    for (int ks = 0; ks < 4; ++ks) {
        int row = q0 + wave * 16 + lr;
        qf[ks] = *reinterpret_cast<const bf16x8*>(q_rope + ((size_t)h * LSEQ + row) * HD + ks * 32 + lg * 8);
    }
    f32x4 o[8] = {};
    float mrun[4], lrun[4];
    #pragma unroll
    for (int r = 0; r < 4; ++r) { mrun[r] = -1e30f; lrun[r] = 0.f; }

    for (int kt = 0; kt < LSEQ; kt += 64) {
        #pragma unroll
        for (int ii = 0; ii < 4; ++ii) {
            int c = tid + ii * 256;
            int krow = c >> 4, kc = c & 15;
            uint4 va = *reinterpret_cast<const uint4*>(Kb + (size_t)(kt + krow) * HD + kc * 8);
            *reinterpret_cast<uint4*>(reinterpret_cast<char*>(Ks) + krow * 256 + ((kc ^ (krow & 15)) << 4)) = va;
            int dr = c >> 3, vc = c & 7;
            uint4 vb = *reinterpret_cast<const uint4*>(Vb + (size_t)dr * LSEQ + kt + vc * 8);
            *reinterpret_cast<uint4*>(reinterpret_cast<char*>(Vs) + dr * 128 + ((vc ^ (dr & 7)) << 4)) = vb;
        }
        __syncthreads();
        f32x4 s[4] = {};
        __builtin_amdgcn_s_setprio(1);
        #pragma unroll
        for (int ks = 0; ks < 4; ++ks) {
            bf16x8 kf[4];
            #pragma unroll
            for (int j = 0; j < 4; ++j) {
                int krow = j * 16 + lr;
                int cc = ks * 4 + lg;
                kf[j] = *reinterpret_cast<const bf16x8*>(reinterpret_cast<char*>(Ks) + krow * 256 + ((cc ^ (krow & 15)) << 4));
            }
            #pragma unroll
            for (int j = 0; j < 4; ++j)
                s[j] = __builtin_amdgcn_mfma_f32_16x16x32_bf16(qf[ks], kf[j], s[j], 0, 0, 0);
        }
        __builtin_amdgcn_s_setprio(0);
        float alpha[4];
        #pragma unroll
        for (int r = 0; r < 4; ++r) {
            float v0 = s[0][r] * SC, v1 = s[1][r] * SC;
            float v2 = s[2][r] * SC, v3 = s[3][r] * SC;
            float mx = fmaxf(fmaxf(v0, v1), fmaxf(v2, v3));
            #pragma unroll
            for (int off = 1; off < 16; off <<= 1) mx = fmaxf(mx, __shfl_xor(mx, off));
            float mnew = fmaxf(mrun[r], mx);
            float al = __expf(mrun[r] - mnew);
            float p0 = __expf(v0 - mnew), p1 = __expf(v1 - mnew);
            float p2 = __expf(v2 - mnew), p3 = __expf(v3 - mnew);
            float rs2 = p0 + p1 + p2 + p3;
            #pragma unroll
            for (int off = 1; off < 16; off <<= 1) rs2 += __shfl_xor(rs2, off);
            lrun[r] = lrun[r] * al + rs2;
            mrun[r] = mnew;
            alpha[r] = al;
            s[0][r] = p0; s[1][r] = p1; s[2][r] = p2; s[3][r] = p3;
        }
        #pragma unroll
        for (int j8 = 0; j8 < 8; ++j8)
            #pragma unroll
            for (int r = 0; r < 4; ++r) o[j8][r] *= alpha[r];
        #pragma unroll
        for (int j = 0; j < 4; ++j)
            #pragma unroll
            for (int r = 0; r < 4; ++r) {
                int ql = lg * 4 + r;
                Ps[wave * 1152 + ql * 72 + j * 16 + lr] = f2bf(s[j][r]);
            }
        __syncthreads();   // orders P ds_writes against vector re-reads (R9 lesson)
        bf16x8 pa[2];
        #pragma unroll
        for (int ks2 = 0; ks2 < 2; ++ks2)
            pa[ks2] = *reinterpret_cast<const bf16x8*>(Ps + wave * 1152 + lr * 72 + ks2 * 32 + lg * 8);
        __builtin_amdgcn_s_setprio(1);
        #pragma unroll
        for (int j8 = 0; j8 < 8; ++j8) {
            int d = j8 * 16 + lr;
            #pragma unroll
            for (int ks2 = 0; ks2 < 2; ++ks2) {
                int cc = ks2 * 4 + lg;
                bf16x8 vf = *reinterpret_cast<const bf16x8*>(reinterpret_cast<char*>(Vs) + d * 128 + ((cc ^ (d & 7)) << 4));
                o[j8] = __builtin_amdgcn_mfma_f32_16x16x32_bf16(pa[ks2], vf, o[j8], 0, 0, 0);
            }
        }
        __builtin_amdgcn_s_setprio(0);
        __syncthreads();   // all reads of Ks/Vs/Ps done before next iter's writes
    }

    // epilogue: normalize, optionally add ip-attention (block-uniform: q0>=256), write concat bf16
    bool ip = (q0 >= 256);
    #pragma unroll
    for (int r = 0; r < 4; ++r) {
        int mrow = q0 + wave * 16 + lg * 4 + r;
        float inv = 1.0f / lrun[r];
        float od[8];
        #pragma unroll
        for (int j8 = 0; j8 < 8; ++j8) od[j8] = o[j8][r] * inv;
        if (ip) {
            float mask = img_mask[mrow - 256];
            float qr[8];
            #pragma unroll
            for (int j8 = 0; j8 < 8; ++j8)
                qr[j8] = bf2f(q_rms[((size_t)h * LSEQ + mrow) * HD + j8 * 16 + lr]);
            float scv[16];
            #pragma unroll
            for (int j = 0; j < 16; ++j) {
                const float* kb = ipk + ((size_t)h * 16 + j) * HD;
                float part = 0.f;
                #pragma unroll
                for (int j8 = 0; j8 < 8; ++j8) part += qr[j8] * kb[j8 * 16 + lr];
                #pragma unroll
                for (int off = 1; off < 16; off <<= 1) part += __shfl_xor(part, off);
                scv[j] = part * SC;
            }
            float mx = scv[0];
            #pragma unroll
            for (int j = 1; j < 16; ++j) mx = fmaxf(mx, scv[j]);
            float sum = 0.f;
            #pragma unroll
            for (int j = 0; j < 16; ++j) { scv[j] = __expf(scv[j] - mx); sum += scv[j]; }
            float f = 0.6f * mask / sum;
            #pragma unroll
            for (int j = 0; j < 16; ++j) {
                const float* vb = ipv + ((size_t)h * 16 + j) * HD;
                float p = f * scv[j];
                #pragma unroll
                for (int j8 = 0; j8 < 8; ++j8) od[j8] += p * vb[j8 * 16 + lr];
            }
        }
        ushort_t* crow = concat + (size_t)mrow * K2 + h * HD;
        #pragma unroll
        for (int j8 = 0; j8 < 8; ++j8) crow[j8 * 16 + lr] = f2bf(od[j8]);
    }
}

extern "C" void kernel_launch(void* const* d_in, const int* in_sizes, int n_in,
                              void* d_out, int out_size, void* d_ws, size_t ws_size,
                              hipStream_t stream)
{
    (void)in_sizes; (void)n_in; (void)out_size; (void)ws_size;
    const float* x         = (const float*)d_in[0];
    const float* vec       = (const float*)d_in[1];
    const float* pe        = (const float*)d_in[2];
    const float* img_mask  = (const float*)d_in[3];
    const float* image_emb = (const float*)d_in[4];
    const float* mod_w     = (const float*)d_in[5];
    const float* mod_b     = (const float*)d_in[6];
    const float* lin1_w    = (const float*)d_in[7];
    const float* lin1_b    = (const float*)d_in[8];
    const float* q_scale   = (const float*)d_in[9];
    const float* k_scale   = (const float*)d_in[10];
    const float* lin2_w    = (const float*)d_in[11];
    const float* lin2_b    = (const float*)d_in[12];
    const float* ipk_w     = (const float*)d_in[13];
    const float* ipv_w     = (const float*)d_in[14];
    float* dout = (float*)d_out;

    char* wp = (char*)d_ws;
    auto alloc = [&](size_t bytes) { char* p = wp; wp += (bytes + 255) & ~(size_t)255; return p; };
    // persistent through GEMM2:
    float*    mod     = (float*)   alloc((size_t)9216 * 4);
    ushort_t* concat  = (ushort_t*)alloc((size_t)LSEQ * K2 * 2);
    ushort_t* lin2_bf = (ushort_t*)alloc((size_t)HID * K2 * 2);
    float*    ipk     = (float*)   alloc((size_t)NH * 16 * HD * 4);
    float*    ipv     = (float*)   alloc((size_t)NH * 16 * HD * 4);
    // union region: all dead before GEMM2; bf16 partial (4 * LSEQ * HID * 2B = 50.3 MB) aliases it
    char* ubase = wp;
    ushort_t* lin1_bf = (ushort_t*)alloc((size_t)N1 * HID * 2);     // 132.1 MB
    ushort_t* xmod    = (ushort_t*)alloc((size_t)LSEQ * HID * 2);
    ushort_t* qkv     = (ushort_t*)alloc((size_t)LSEQ * 3 * HID * 2);
    ushort_t* q_rope  = (ushort_t*)alloc((size_t)NH * LSEQ * HD * 2);
    ushort_t* k_rope  = (ushort_t*)alloc((size_t)NH * LSEQ * HD * 2);
    ushort_t* q_rms   = (ushort_t*)alloc((size_t)NH * LSEQ * HD * 2);
    ushort_t* v_t     = (ushort_t*)alloc((size_t)NH * HD * LSEQ * 2);
    ushort_t* partial = (ushort_t*)ubase;   // 50.3 MB <= union span

    hipFuncSetAttribute((const void*)k_gemm8, hipFuncAttributeMaxDynamicSharedMemorySize, 163840);
    hipFuncSetAttribute((const void*)k_gemm4, hipFuncAttributeMaxDynamicSharedMemorySize, 81920);

    k_cvt2  <<<dim3(4096), dim3(256), 0, stream>>>(lin1_w, lin1_bf, N1 * HID,
                                                   lin2_w, lin2_bf, HID * K2);
    k_mod   <<<dim3(9216 / 4), dim3(256), 0, stream>>>(vec, mod_w, mod_b, mod);
    k_lnmod <<<dim3(LSEQ), dim3(256), 0, stream>>>(x, mod, xmod);
    k_gemm8 <<<dim3(84, 8), dim3(512), 163840, stream>>>(xmod, lin1_bf, lin1_b, qkv, concat);
    k_qkv   <<<dim3(32, NH), dim3(256), 0, stream>>>(qkv, pe, q_scale, k_scale,
                                                     q_rope, k_rope, q_rms, v_t);
    k_ipgemv<<<dim3(2 * HID / 4), dim3(256), 0, stream>>>(image_emb, ipk_w, ipv_w, ipk, ipv);
    k_ipkrms<<<dim3(NH * 16 / 4), dim3(256), 0, stream>>>(ipk);
    k_attn  <<<dim3(32, NH), dim3(256), 0, stream>>>(q_rope, k_rope, v_t, q_rms,
                                                     ipk, ipv, img_mask, concat);
    k_gemm4 <<<dim3(24, 16, 4), dim3(256), 81920, stream>>>(concat, lin2_bf, 3840, partial);
    k_red   <<<dim3(LSEQ * HID / 2048), dim3(256), 0, stream>>>(partial, lin2_b, x, mod, dout);
}

// Round 15
// 946.805 us; speedup vs baseline: 1.0881x; 1.0881x over previous
//
#include <hip/hip_runtime.h>

#define HID 3072
#define LSEQ 2048
#define NH 24
#define HD 128
#define N1 21504   // 3*HID + MLP
#define K2 15360   // HID + MLP

typedef unsigned short ushort_t;
typedef __attribute__((ext_vector_type(8))) short bf16x8;
typedef __attribute__((ext_vector_type(4))) float f32x4;

__device__ __forceinline__ unsigned short f2bf(float f) {
    union { float f; unsigned int u; } v; v.f = f;
    unsigned int u = v.u;
    u += 0x7fffu + ((u >> 16) & 1u);   // RNE
    return (unsigned short)(u >> 16);
}
__device__ __forceinline__ float bf2f(unsigned short s) {
    union { unsigned int u; float f; } v; v.u = ((unsigned int)s) << 16;
    return v.f;
}
__device__ __forceinline__ float gelu_tanh(float x) {
    float u = 0.7978845608028654f * (x + 0.044715f * x * x * x);
    float t = 2.0f / (1.0f + __expf(-2.0f * u)) - 1.0f;
    return 0.5f * x * (1.0f + t);
}
__device__ __forceinline__ void gload_lds16(const ushort_t* g, ushort_t* l) {
    __builtin_amdgcn_global_load_lds((const __attribute__((address_space(1))) void*)g,
                                     (__attribute__((address_space(3))) void*)l, 16, 0, 0);
}

// ---------------- f32 -> bf16 conversion of both weight matrices, one launch ----------------
__global__ __launch_bounds__(256) void k_cvt2(const float* __restrict__ s1,
    ushort_t* __restrict__ d1, int n1, const float* __restrict__ s2,
    ushort_t* __restrict__ d2, int n2)
{
    int stride = gridDim.x * 256 * 8;
    int base = (blockIdx.x * 256 + threadIdx.x) * 8;
    for (int i = base; i < n1; i += stride) {
        float4 a = *reinterpret_cast<const float4*>(s1 + i);
        float4 b = *reinterpret_cast<const float4*>(s1 + i + 4);
        uint4 pk;
        pk.x = (unsigned)f2bf(a.x) | ((unsigned)f2bf(a.y) << 16);
        pk.y = (unsigned)f2bf(a.z) | ((unsigned)f2bf(a.w) << 16);
        pk.z = (unsigned)f2bf(b.x) | ((unsigned)f2bf(b.y) << 16);
        pk.w = (unsigned)f2bf(b.z) | ((unsigned)f2bf(b.w) << 16);
        *reinterpret_cast<uint4*>(d1 + i) = pk;
    }
    for (int i = base; i < n2; i += stride) {
        float4 a = *reinterpret_cast<const float4*>(s2 + i);
        float4 b = *reinterpret_cast<const float4*>(s2 + i + 4);
        uint4 pk;
        pk.x = (unsigned)f2bf(a.x) | ((unsigned)f2bf(a.y) << 16);
        pk.y = (unsigned)f2bf(a.z) | ((unsigned)f2bf(a.w) << 16);
        pk.z = (unsigned)f2bf(b.x) | ((unsigned)f2bf(b.y) << 16);
        pk.w = (unsigned)f2bf(b.z) | ((unsigned)f2bf(b.w) << 16);
        *reinterpret_cast<uint4*>(d2 + i) = pk;
    }
}

// ---------------- mod = silu(vec) @ mod_w.T + mod_b ----------------
__global__ __launch_bounds__(256) void k_mod(const float* __restrict__ vec,
    const float* __restrict__ mw, const float* __restrict__ mb, float* __restrict__ mod) {
    __shared__ __align__(16) float sv[HID];
    int tid = threadIdx.x;
    for (int i = tid; i < HID; i += 256) {
        float v = vec[i];
        sv[i] = v / (1.0f + __expf(-v));
    }
    __syncthreads();
    int wave = tid >> 6, lane = tid & 63;
    int n = blockIdx.x * 4 + wave;
    const float* w = mw + (size_t)n * HID;
    float acc = 0.0f;
    for (int k = lane * 4; k < HID; k += 256) {
        float4 wv = *reinterpret_cast<const float4*>(w + k);
        float4 s  = *reinterpret_cast<const float4*>(sv + k);
        acc += wv.x * s.x + wv.y * s.y + wv.z * s.z + wv.w * s.w;
    }
    #pragma unroll
    for (int off = 1; off < 64; off <<= 1) acc += __shfl_xor(acc, off);
    if (lane == 0) mod[n] = acc + mb[n];
}

// ---------------- LayerNorm + (1+scale)*ln + shift -> bf16 ----------------
__global__ __launch_bounds__(256) void k_lnmod(const float* __restrict__ x,
    const float* __restrict__ mod, ushort_t* __restrict__ xmod) {
    int row = blockIdx.x, tid = threadIdx.x;
    const float4* xr = reinterpret_cast<const float4*>(x + (size_t)row * HID);
    float4 v[3];
    float s = 0.f, sq = 0.f;
    #pragma unroll
    for (int i = 0; i < 3; ++i) {
        v[i] = xr[tid + i * 256];
        s  += v[i].x + v[i].y + v[i].z + v[i].w;
        sq += v[i].x * v[i].x + v[i].y * v[i].y + v[i].z * v[i].z + v[i].w * v[i].w;
    }
    #pragma unroll
    for (int off = 1; off < 64; off <<= 1) { s += __shfl_xor(s, off); sq += __shfl_xor(sq, off); }
    __shared__ float rs[4], rq[4];
    int wave = tid >> 6, lane = tid & 63;
    if (lane == 0) { rs[wave] = s; rq[wave] = sq; }
    __syncthreads();
    s  = rs[0] + rs[1] + rs[2] + rs[3];
    sq = rq[0] + rq[1] + rq[2] + rq[3];
    float mean = s * (1.0f / HID);
    float var = sq * (1.0f / HID) - mean * mean;
    float rstd = rsqrtf(var + 1e-6f);
    ushort_t* orow = xmod + (size_t)row * HID;
    #pragma unroll
    for (int i = 0; i < 3; ++i) {
        int c = (tid + i * 256) * 4;
        float4 sc = *reinterpret_cast<const float4*>(mod + HID + c);
        float4 sh = *reinterpret_cast<const float4*>(mod + c);
        float o0 = (1.f + sc.x) * ((v[i].x - mean) * rstd) + sh.x;
        float o1 = (1.f + sc.y) * ((v[i].y - mean) * rstd) + sh.y;
        float o2 = (1.f + sc.z) * ((v[i].z - mean) * rstd) + sh.z;
        float o3 = (1.f + sc.w) * ((v[i].w - mean) * rstd) + sh.w;
        *reinterpret_cast<ushort4*>(orow + c) = make_ushort4(f2bf(o0), f2bf(o1), f2bf(o2), f2bf(o3));
    }
}

#define MFMA_CLUSTER(PH, AF)                                                          \
    do {                                                                              \
        __builtin_amdgcn_s_setprio(1);                                                \
        _Pragma("unroll") for (int i_ = 0; i_ < 2; ++i_)                              \
        _Pragma("unroll") for (int nj_ = 0; nj_ < 4; ++nj_)                           \
        _Pragma("unroll") for (int kh_ = 0; kh_ < 2; ++kh_)                           \
            acc[2 * (PH) + i_][nj_] = __builtin_amdgcn_mfma_f32_16x16x32_bf16(        \
                AF[i_][kh_], bfrag[nj_][kh_], acc[2 * (PH) + i_][nj_], 0, 0, 0);      \
        __builtin_amdgcn_s_setprio(0);                                                \
    } while (0)

// ---------------- GEMM1: 256x256, BK=64, 8 waves, 160KB LDS (best-measured) ----------------
__global__ __launch_bounds__(512) void k_gemm8(
    const ushort_t* __restrict__ A, const ushort_t* __restrict__ W,
    const float* __restrict__ bias,
    ushort_t* __restrict__ out_qkv, ushort_t* __restrict__ out_concat)
{
    extern __shared__ __align__(16) char smem_raw[];
    ushort_t* smem = (ushort_t*)smem_raw;   // [A0|A1|A2: 3*16384][B0|B1: 2*16384] elements
    const int Ks = HID;
    int tid = threadIdx.x;
    int wid = tid >> 6, l = tid & 63;
    int wm = wid >> 2, wn = wid & 3;
    int lr = l & 15, lg = l >> 4;

    int flat = blockIdx.y * 84 + blockIdx.x;
    int nf = (flat & 7) * 84 + (flat >> 3);
    int mt = nf & 7, nt = nf >> 3;
    int m0 = mt * 256, n0 = nt * 256;
    int NT = Ks >> 6;

    int lrow = l >> 3;
    int lc   = (l & 7) ^ lrow;       // pre-swizzled source chunk
    int arow_st = wm * 128 + wn * 32 + lrow;
    int bhalf = wn >> 1, ridx = wm * 2 + (wn & 1);
    int brow_st = bhalf * 128 + ridx * 32 + lrow;
    const ushort_t* aSrc = A + (size_t)(m0 + arow_st) * Ks + lc * 8;
    const ushort_t* bSrc = W + (size_t)(n0 + brow_st) * Ks + lc * 8;
    int aDst = (wm * 128 + wn * 32) * 64;
    int bDst = (bhalf * 128 + ridx * 32) * 64;

    auto stageA = [&](int t, int buf, int c) {
        gload_lds16(aSrc + (size_t)c * 8 * Ks + (size_t)t * 64,
                    smem + buf * 16384 + aDst + c * 512);
    };
    auto stageB = [&](int t, int c) {
        gload_lds16(bSrc + (size_t)c * 8 * Ks + (size_t)t * 64,
                    smem + 49152 + (t & 1) * 16384 + bDst + c * 512);
    };
    auto readA = [&](int buf, int row, int ccc) {
        return *reinterpret_cast<const bf16x8*>(smem + buf * 16384 + row * 64 + ((ccc ^ (row & 7)) << 3));
    };
    auto readB = [&](int p, int row, int ccc) {
        return *reinterpret_cast<const bf16x8*>(smem + 49152 + p * 16384 + row * 64 + ((ccc ^ (row & 7)) << 3));
    };

    f32x4 acc[8][4] = {};

    #pragma unroll
    for (int c = 0; c < 4; ++c) stageA(0, 0, c);
    #pragma unroll
    for (int c = 0; c < 4; ++c) stageB(0, c);
    #pragma unroll
    for (int c = 0; c < 4; ++c) stageA(1, 1, c);
    #pragma unroll
    for (int c = 0; c < 4; ++c) stageB(1, c);
    asm volatile("s_waitcnt vmcnt(8)" ::: "memory");
    __builtin_amdgcn_s_barrier();

    int pA = 0, pA2 = 2;
    for (int t = 0; t < NT; ++t) {
        int pB = t & 1;
        bf16x8 bfrag[4][2], af0[2][2], af1[2][2], af2[2][2], af3[2][2];
        #pragma unroll
        for (int nj = 0; nj < 4; ++nj)
            #pragma unroll
            for (int kh = 0; kh < 2; ++kh)
                bfrag[nj][kh] = readB(pB, wn * 64 + nj * 16 + lr, kh * 4 + lg);
        #pragma unroll
        for (int i = 0; i < 2; ++i)
            #pragma unroll
            for (int kh = 0; kh < 2; ++kh)
                af0[i][kh] = readA(pA, wm * 128 + i * 16 + lr, kh * 4 + lg);
        if (t + 2 < NT) {
            stageA(t + 2, pA2, 0); stageA(t + 2, pA2, 1);
            stageA(t + 2, pA2, 2); stageA(t + 2, pA2, 3);
        }
        #pragma unroll
        for (int i = 0; i < 2; ++i)
            #pragma unroll
            for (int kh = 0; kh < 2; ++kh)
                af1[i][kh] = readA(pA, wm * 128 + (2 + i) * 16 + lr, kh * 4 + lg);
        MFMA_CLUSTER(0, af0);
        #pragma unroll
        for (int i = 0; i < 2; ++i)
            #pragma unroll
            for (int kh = 0; kh < 2; ++kh)
                af2[i][kh] = readA(pA, wm * 128 + (4 + i) * 16 + lr, kh * 4 + lg);
        MFMA_CLUSTER(1, af1);
        __builtin_amdgcn_s_barrier();   // all waves consumed B(t)
        if (t + 2 < NT) {
            stageB(t + 2, 0); stageB(t + 2, 1);
            stageB(t + 2, 2); stageB(t + 2, 3);
        }
        #pragma unroll
        for (int i = 0; i < 2; ++i)
            #pragma unroll
            for (int kh = 0; kh < 2; ++kh)
                af3[i][kh] = readA(pA, wm * 128 + (6 + i) * 16 + lr, kh * 4 + lg);
        MFMA_CLUSTER(2, af2);
        MFMA_CLUSTER(3, af3);
        if (t + 2 < NT)      asm volatile("s_waitcnt vmcnt(8)" ::: "memory");
        else if (t + 1 < NT) asm volatile("s_waitcnt vmcnt(0)" ::: "memory");
        __builtin_amdgcn_s_barrier();
        pA  = (pA  + 1 == 3) ? 0 : pA  + 1;
        pA2 = (pA2 + 1 == 3) ? 0 : pA2 + 1;
    }

    #pragma unroll
    for (int nj = 0; nj < 4; ++nj) {
        int col = n0 + wn * 64 + nj * 16 + lr;
        float b = bias[col];
        #pragma unroll
        for (int mi = 0; mi < 8; ++mi) {
            int rbase = m0 + wm * 128 + mi * 16 + lg * 4;
            #pragma unroll
            for (int r = 0; r < 4; ++r) {
                int mrow = rbase + r;
                float val = acc[mi][nj][r] + b;
                if (col < 3 * HID) {
                    out_qkv[(size_t)mrow * (3 * HID) + col] = f2bf(val);
                } else {
                    out_concat[(size_t)mrow * K2 + HID + (col - 3 * HID)] = f2bf(gelu_tanh(val));
                }
            }
        }
    }
}

#define MFMA_CL4(PH, AF)                                                              \
    do {                                                                              \
        __builtin_amdgcn_s_setprio(1);                                                \
        _Pragma("unroll") for (int nj_ = 0; nj_ < 4; ++nj_)                           \
        _Pragma("unroll") for (int kh_ = 0; kh_ < 2; ++kh_)                           \
            acc[(PH)][nj_] = __builtin_amdgcn_mfma_f32_16x16x32_bf16(                 \
                AF[kh_], bfrag[nj_][kh_], acc[(PH)][nj_], 0, 0, 0);                   \
        __builtin_amdgcn_s_setprio(0);                                                \
    } while (0)

// ---------------- GEMM2: 128x128, BK=64, 4 waves, 80KB LDS, split-K(4), bf16 partials ----------------
__global__ __launch_bounds__(256) void k_gemm4(
    const ushort_t* __restrict__ A, const ushort_t* __restrict__ W,
    int klen, ushort_t* __restrict__ part)
{
    extern __shared__ __align__(16) char smem_raw[];
    ushort_t* smem = (ushort_t*)smem_raw;   // [A0|A1|A2: 3x8192][B0|B1: 2x8192] = 80 KB
    const int Ks = K2;
    int tid = threadIdx.x;
    int wave = tid >> 6, l = tid & 63;
    int wm = wave >> 1, wn = wave & 1;
    int lr = l & 15, lg = l >> 4;

    int flat = blockIdx.y * 24 + blockIdx.x;
    int nf = (flat & 7) * 48 + (flat >> 3);
    int mt = nf & 15, nt = nf >> 4;
    int m0 = mt * 128, n0 = nt * 128;
    int koff = blockIdx.z * klen;
    int NT = klen >> 6;

    int lrow = l >> 3;
    int lc   = (l & 7) ^ lrow;
    const ushort_t* aSrc = A + (size_t)(m0 + wave * 32 + lrow) * Ks + koff + lc * 8;
    const ushort_t* bSrc = W + (size_t)(n0 + wave * 32 + lrow) * Ks + koff + lc * 8;
    int dstBase = wave * 2048;

    auto stageA = [&](int t, int buf) {
        #pragma unroll
        for (int c = 0; c < 4; ++c)
            gload_lds16(aSrc + (size_t)c * 8 * Ks + (size_t)t * 64,
                        smem + buf * 8192 + dstBase + c * 512);
    };
    auto stageB = [&](int t) {
        #pragma unroll
        for (int c = 0; c < 4; ++c)
            gload_lds16(bSrc + (size_t)c * 8 * Ks + (size_t)t * 64,
                        smem + 24576 + (t & 1) * 8192 + dstBase + c * 512);
    };
    auto readA = [&](int buf, int row, int ccc) {
        return *reinterpret_cast<const bf16x8*>(smem + buf * 8192 + row * 64 + ((ccc ^ (row & 7)) << 3));
    };
    auto readB = [&](int p, int row, int ccc) {
        return *reinterpret_cast<const bf16x8*>(smem + 24576 + p * 8192 + row * 64 + ((ccc ^ (row & 7)) << 3));
    };

    f32x4 acc[4][4] = {};

    stageA(0, 0); stageB(0); stageA(1, 1); stageB(1);
    asm volatile("s_waitcnt vmcnt(8)" ::: "memory");
    __builtin_amdgcn_s_barrier();

    int pA = 0, pA2 = 2;
    for (int t = 0; t < NT; ++t) {
        int pB = t & 1;
        bf16x8 bfrag[4][2], af0[2], af1[2], af2[2], af3[2];
        #pragma unroll
        for (int nj = 0; nj < 4; ++nj)
            #pragma unroll
            for (int kh = 0; kh < 2; ++kh)
                bfrag[nj][kh] = readB(pB, wn * 64 + nj * 16 + lr, kh * 4 + lg);
        #pragma unroll
        for (int kh = 0; kh < 2; ++kh)
            af0[kh] = readA(pA, wm * 64 + lr, kh * 4 + lg);
        if (t + 2 < NT) stageA(t + 2, pA2);
        #pragma unroll
        for (int kh = 0; kh < 2; ++kh)
            af1[kh] = readA(pA, wm * 64 + 16 + lr, kh * 4 + lg);
        MFMA_CL4(0, af0);
        #pragma unroll
        for (int kh = 0; kh < 2; ++kh)
            af2[kh] = readA(pA, wm * 64 + 32 + lr, kh * 4 + lg);
        MFMA_CL4(1, af1);
        __builtin_amdgcn_s_barrier();
        if (t + 2 < NT) stageB(t + 2);
        #pragma unroll
        for (int kh = 0; kh < 2; ++kh)
            af3[kh] = readA(pA, wm * 64 + 48 + lr, kh * 4 + lg);
        MFMA_CL4(2, af2);
        MFMA_CL4(3, af3);
        if (t + 2 < NT)      asm volatile("s_waitcnt vmcnt(8)" ::: "memory");
        else if (t + 1 < NT) asm volatile("s_waitcnt vmcnt(0)" ::: "memory");
        __builtin_amdgcn_s_barrier();
        pA  = (pA  + 1 == 3) ? 0 : pA  + 1;
        pA2 = (pA2 + 1 == 3) ? 0 : pA2 + 1;
    }

    #pragma unroll
    for (int nj = 0; nj < 4; ++nj) {
        int col = n0 + wn * 64 + nj * 16 + lr;
        #pragma unroll
        for (int mi = 0; mi < 4; ++mi) {
            int rbase = m0 + wm * 64 + mi * 16 + lg * 4;
            #pragma unroll
            for (int r = 0; r < 4; ++r) {
                int mrow = rbase + r;
                part[(size_t)blockIdx.z * LSEQ * HID + (size_t)mrow * HID + col] = f2bf(acc[mi][nj][r]);
            }
        }
    }
}

// ---------------- split-K(4) bf16 reduce + bias + gate + residual ----------------
__global__ __launch_bounds__(256) void k_red(const ushort_t* __restrict__ part,
    const float* __restrict__ bias, const float* __restrict__ xres,
    const float* __restrict__ mod, float* __restrict__ dout)
{
    size_t base = ((size_t)blockIdx.x * 256 + threadIdx.x) * 8;
    int col = (int)(base % HID);
    float s[8] = {0.f, 0.f, 0.f, 0.f, 0.f, 0.f, 0.f, 0.f};
    #pragma unroll
    for (int z = 0; z < 4; ++z) {
        uint4 pv = *reinterpret_cast<const uint4*>(part + (size_t)z * LSEQ * HID + base);
        unsigned w0 = pv.x, w1 = pv.y, w2 = pv.z, w3 = pv.w;
        s[0] += bf2f((ushort_t)(w0 & 0xffffu)); s[1] += bf2f((ushort_t)(w0 >> 16));
        s[2] += bf2f((ushort_t)(w1 & 0xffffu)); s[3] += bf2f((ushort_t)(w1 >> 16));
        s[4] += bf2f((ushort_t)(w2 & 0xffffu)); s[5] += bf2f((ushort_t)(w2 >> 16));
        s[6] += bf2f((ushort_t)(w3 & 0xffffu)); s[7] += bf2f((ushort_t)(w3 >> 16));
    }
    float4 bb0 = *reinterpret_cast<const float4*>(bias + col);
    float4 bb1 = *reinterpret_cast<const float4*>(bias + col + 4);
    float4 gg0 = *reinterpret_cast<const float4*>(mod + 2 * HID + col);
    float4 gg1 = *reinterpret_cast<const float4*>(mod + 2 * HID + col + 4);
    float4 xx0 = *reinterpret_cast<const float4*>(xres + base);
    float4 xx1 = *reinterpret_cast<const float4*>(xres + base + 4);
    float4 o0, o1;
    o0.x = xx0.x + gg0.x * (s[0] + bb0.x);
    o0.y = xx0.y + gg0.y * (s[1] + bb0.y);
    o0.z = xx0.z + gg0.z * (s[2] + bb0.z);
    o0.w = xx0.w + gg0.w * (s[3] + bb0.w);
    o1.x = xx1.x + gg1.x * (s[4] + bb1.x);
    o1.y = xx1.y + gg1.y * (s[5] + bb1.y);
    o1.z = xx1.z + gg1.z * (s[6] + bb1.z);
    o1.w = xx1.w + gg1.w * (s[7] + bb1.w);
    *reinterpret_cast<float4*>(dout + base) = o0;
    *reinterpret_cast<float4*>(dout + base + 4) = o1;
}

// ---------------- per-(h,l): RMS(q,k) + RoPE, write q_rope/k_rope/q_rms bf16 + V^T ----------------
__global__ __launch_bounds__(256) void k_qkv(const ushort_t* __restrict__ qkv,
    const float* __restrict__ pe, const float* __restrict__ q_scale, const float* __restrict__ k_scale,
    ushort_t* __restrict__ q_rope, ushort_t* __restrict__ k_rope,
    ushort_t* __restrict__ q_rms, ushort_t* __restrict__ v_t)
{
    __shared__ ushort_t vtile[64][132];
    int h = blockIdx.y, l0 = blockIdx.x * 64;
    int wave = threadIdx.x >> 6, lane = threadIdx.x & 63;
    int d0 = lane * 2;
    float qs0 = q_scale[d0], qs1 = q_scale[d0 + 1];
    float ks0 = k_scale[d0], ks1 = k_scale[d0 + 1];
    for (int it = 0; it < 16; ++it) {
        int ll = it * 4 + wave;
        int l = l0 + ll;
        const ushort_t* base = qkv + (size_t)l * (3 * HID) + h * HD + d0;
        unsigned qw = *reinterpret_cast<const unsigned*>(base);
        unsigned kw = *reinterpret_cast<const unsigned*>(base + HID);
        unsigned vw = *reinterpret_cast<const unsigned*>(base + 2 * HID);
        float qx = bf2f((ushort_t)(qw & 0xffffu)), qy = bf2f((ushort_t)(qw >> 16));
        float kx = bf2f((ushort_t)(kw & 0xffffu)), ky = bf2f((ushort_t)(kw >> 16));
        float sq = qx * qx + qy * qy;
        float sk = kx * kx + ky * ky;
        #pragma unroll
        for (int off = 1; off < 64; off <<= 1) { sq += __shfl_xor(sq, off); sk += __shfl_xor(sk, off); }
        float rqv = rsqrtf(sq * (1.0f / HD) + 1e-6f);
        float rkv = rsqrtf(sk * (1.0f / HD) + 1e-6f);
        float qnx = qx * rqv * qs0, qny = qy * rqv * qs1;
        float knx = kx * rkv * ks0, kny = ky * rkv * ks1;
        float4 p = *reinterpret_cast<const float4*>(pe + ((size_t)l * 64 + lane) * 4);
        size_t off_hl = ((size_t)h * LSEQ + l) * HD + d0;
        *reinterpret_cast<unsigned*>(q_rms + off_hl) = (unsigned)f2bf(qnx) | ((unsigned)f2bf(qny) << 16);
        float qrx = p.x * qnx + p.y * qny, qry = p.z * qnx + p.w * qny;
        float krx = p.x * knx + p.y * kny, kry = p.z * knx + p.w * kny;
        *reinterpret_cast<unsigned*>(q_rope + off_hl) = (unsigned)f2bf(qrx) | ((unsigned)f2bf(qry) << 16);
        *reinterpret_cast<unsigned*>(k_rope + off_hl) = (unsigned)f2bf(krx) | ((unsigned)f2bf(kry) << 16);
        vtile[ll][d0] = (ushort_t)(vw & 0xffffu);
        vtile[ll][d0 + 1] = (ushort_t)(vw >> 16);
    }
    __syncthreads();
    int d = threadIdx.x >> 1, half = threadIdx.x & 1;
    ushort_t* dst = v_t + ((size_t)h * HD + d) * LSEQ + l0 + half * 32;
    #pragma unroll
    for (int g = 0; g < 4; ++g) {
        unsigned w0, w1, w2, w3;
        int lb = half * 32 + g * 8;
        w0 = (unsigned)vtile[lb + 0][d] | ((unsigned)vtile[lb + 1][d] << 16);
        w1 = (unsigned)vtile[lb + 2][d] | ((unsigned)vtile[lb + 3][d] << 16);
        w2 = (unsigned)vtile[lb + 4][d] | ((unsigned)vtile[lb + 5][d] << 16);
        w3 = (unsigned)vtile[lb + 6][d] | ((unsigned)vtile[lb + 7][d] << 16);
        reinterpret_cast<uint4*>(dst)[g] = make_uint4(w0, w1, w2, w3);
    }
}

// ---------------- ip k/v projections ----------------
__global__ __launch_bounds__(256) void k_ipgemv(const float* __restrict__ emb,
    const float* __restrict__ wk, const float* __restrict__ wv,
    float* __restrict__ ipk, float* __restrict__ ipv)
{
    int task = blockIdx.x * 4 + (threadIdx.x >> 6);
    int lane = threadIdx.x & 63;
    int which = task / HID;
    int n = task % HID;
    const float* w = (which ? wv : wk) + (size_t)n * HID;
    float acc[16];
    #pragma unroll
    for (int t = 0; t < 16; ++t) acc[t] = 0.f;
    for (int k = lane; k < HID; k += 64) {
        float wval = w[k];
        #pragma unroll
        for (int t = 0; t < 16; ++t) acc[t] += emb[t * HID + k] * wval;
    }
    #pragma unroll
    for (int off = 1; off < 64; off <<= 1) {
        #pragma unroll
        for (int t = 0; t < 16; ++t) acc[t] += __shfl_xor(acc[t], off);
    }
    if (lane == 0) {
        int hh = n >> 7, d = n & 127;
        float* dstp = which ? ipv : ipk;
        #pragma unroll
        for (int t = 0; t < 16; ++t) dstp[((size_t)hh * 16 + t) * HD + d] = acc[t];
    }
}

__global__ __launch_bounds__(256) void k_ipkrms(float* __restrict__ ipk) {
    int row = blockIdx.x * 4 + (threadIdx.x >> 6);
    int lane = threadIdx.x & 63;
    float2 v = *reinterpret_cast<const float2*>(ipk + (size_t)row * HD + lane * 2);
    float sq = v.x * v.x + v.y * v.y;
    #pragma unroll
    for (int off = 1; off < 64; off <<= 1) sq += __shfl_xor(sq, off);
    float r = rsqrtf(sq * (1.0f / HD) + 1e-5f);
    float2 o; o.x = v.x * r; o.y = v.y * r;
    *reinterpret_cast<float2*>(ipk + (size_t)row * HD + lane * 2) = o;
}

// ---------------- flash attention: QBLK=64, KVBLK=64, 4 waves x 16 q-rows -> concat bf16 ----------------
__global__ __launch_bounds__(256) void k_attn(const ushort_t* __restrict__ q_rope,
    const ushort_t* __restrict__ k_rope, const ushort_t* __restrict__ v_t,
    ushort_t* __restrict__ concat)
{
    __shared__ __align__(16) ushort_t Ks[64 * 128];    // 16 KB
    __shared__ __align__(16) ushort_t Vs[128 * 64];    // 16 KB
    __shared__ __align__(16) ushort_t Ps[4 * 16 * 72]; // 9 KB  -> 41 KB total, 3 blocks/CU
    const float SC = 0.08838834764831845f;
    int h = blockIdx.y, q0 = blockIdx.x * 64;
    int tid = threadIdx.x, wave = tid >> 6, lane = tid & 63;
    int lr = lane & 15, lg = lane >> 4;
    const ushort_t* Kb = k_rope + (size_t)h * LSEQ * HD;
    const ushort_t* Vb = v_t + (size_t)h * HD * LSEQ;
    bf16x8 qf[4];
    #pragma unroll
    for (int ks = 0; ks < 4; ++ks) {
        int row = q0 + wave * 16 + lr;
        qf[ks] = *reinterpret_cast<const bf16x8*>(q_rope + ((size_t)h * LSEQ + row) * HD + ks * 32 + lg * 8);
    }
    f32x4 o[8] = {};
    float mrun[4], lrun[4];
    #pragma unroll
    for (int r = 0; r < 4; ++r) { mrun[r] = -1e30f; lrun[r] = 0.f; }

    for (int kt = 0; kt < LSEQ; kt += 64) {
        #pragma unroll
        for (int ii = 0; ii < 4; ++ii) {
            int c = tid + ii * 256;
            int krow = c >> 4, kc = c & 15;
            uint4 va = *reinterpret_cast<const uint4*>(Kb + (size_t)(kt + krow) * HD + kc * 8);
            *reinterpret_cast<uint4*>(reinterpret_cast<char*>(Ks) + krow * 256 + ((kc ^ (krow & 15)) << 4)) = va;
            int dr = c >> 3, vc = c & 7;
            uint4 vb = *reinterpret_cast<const uint4*>(Vb + (size_t)dr * LSEQ + kt + vc * 8);
            *reinterpret_cast<uint4*>(reinterpret_cast<char*>(Vs) + dr * 128 + ((vc ^ (dr & 7)) << 4)) = vb;
        }
        __syncthreads();
        f32x4 s[4] = {};
        __builtin_amdgcn_s_setprio(1);
        #pragma unroll
        for (int ks = 0; ks < 4; ++ks) {
            bf16x8 kf[4];
            #pragma unroll
            for (int j = 0; j < 4; ++j) {
                int krow = j * 16 + lr;
                int cc = ks * 4 + lg;
                kf[j] = *reinterpret_cast<const bf16x8*>(reinterpret_cast<char*>(Ks) + krow * 256 + ((cc ^ (krow & 15)) << 4));
            }
            #pragma unroll
            for (int j = 0; j < 4; ++j)
                s[j] = __builtin_amdgcn_mfma_f32_16x16x32_bf16(qf[ks], kf[j], s[j], 0, 0, 0);
        }
        __builtin_amdgcn_s_setprio(0);
        float alpha[4];
        #pragma unroll
        for (int r = 0; r < 4; ++r) {
            float v0 = s[0][r] * SC, v1 = s[1][r] * SC;
            float v2 = s[2][r] * SC, v3 = s[3][r] * SC;
            float mx = fmaxf(fmaxf(v0, v1), fmaxf(v2, v3));
            #pragma unroll
            for (int off = 1; off < 16; off <<= 1) mx = fmaxf(mx, __shfl_xor(mx, off));
            float mnew = fmaxf(mrun[r], mx);
            float al = __expf(mrun[r] - mnew);
            float p0 = __expf(v0 - mnew), p1 = __expf(v1 - mnew);
            float p2 = __expf(v2 - mnew), p3 = __expf(v3 - mnew);
            float rs2 = p0 + p1 + p2 + p3;
            #pragma unroll
            for (int off = 1; off < 16; off <<= 1) rs2 += __shfl_xor(rs2, off);
            lrun[r] = lrun[r] * al + rs2;
            mrun[r] = mnew;
            alpha[r] = al;
            s[0][r] = p0; s[1][r] = p1; s[2][r] = p2; s[3][r] = p3;
        }
        #pragma unroll
        for (int j8 = 0; j8 < 8; ++j8)
            #pragma unroll
            for (int r = 0; r < 4; ++r) o[j8][r] *= alpha[r];
        #pragma unroll
        for (int j = 0; j < 4; ++j)
            #pragma unroll
            for (int r = 0; r < 4; ++r) {
                int ql = lg * 4 + r;
                Ps[wave * 1152 + ql * 72 + j * 16 + lr] = f2bf(s[j][r]);
            }
        __syncthreads();   // orders P ds_writes against vector re-reads (R9 lesson)
        bf16x8 pa[2];
        #pragma unroll
        for (int ks2 = 0; ks2 < 2; ++ks2)
            pa[ks2] = *reinterpret_cast<const bf16x8*>(Ps + wave * 1152 + lr * 72 + ks2 * 32 + lg * 8);
        __builtin_amdgcn_s_setprio(1);
        #pragma unroll
        for (int j8 = 0; j8 < 8; ++j8) {
            int d = j8 * 16 + lr;
            #pragma unroll
            for (int ks2 = 0; ks2 < 2; ++ks2) {
                int cc = ks2 * 4 + lg;
                bf16x8 vf = *reinterpret_cast<const bf16x8*>(reinterpret_cast<char*>(Vs) + d * 128 + ((cc ^ (d & 7)) << 4));
                o[j8] = __builtin_amdgcn_mfma_f32_16x16x32_bf16(pa[ks2], vf, o[j8], 0, 0, 0);
            }
        }
        __builtin_amdgcn_s_setprio(0);
        __syncthreads();   // all reads of Ks/Vs/Ps done before next iter's writes
    }
    #pragma unroll
    for (int r = 0; r < 4; ++r) {
        float inv = 1.0f / lrun[r];
        int mrow = q0 + wave * 16 + lg * 4 + r;
        ushort_t* crow = concat + (size_t)mrow * K2 + h * HD;
        #pragma unroll
        for (int j8 = 0; j8 < 8; ++j8)
            crow[j8 * 16 + lr] = f2bf(o[j8][r] * inv);
    }
}

// ---------------- ip attention (K=16) in-place add on concat, masked rows only ----------------
__global__ __launch_bounds__(256) void k_ipattn(const ushort_t* __restrict__ q_rms,
    const float* __restrict__ ipk, const float* __restrict__ ipv,
    const float* __restrict__ img_mask, ushort_t* __restrict__ concat)
{
    int task = blockIdx.x * 4 + (threadIdx.x >> 6);   // 0 .. NH*1792-1
    int lane = threadIdx.x & 63;
    int h = task / 1792;
    int l = 256 + task % 1792;
    int d0 = lane * 2;
    float mask = img_mask[l - 256];
    unsigned cw = *reinterpret_cast<const unsigned*>(concat + (size_t)l * K2 + h * HD + d0);
    float ax = bf2f((ushort_t)(cw & 0xffffu)), ay = bf2f((ushort_t)(cw >> 16));
    unsigned qv = *reinterpret_cast<const unsigned*>(q_rms + ((size_t)h * LSEQ + l) * HD + d0);
    float qx = bf2f((ushort_t)(qv & 0xffffu)), qy = bf2f((ushort_t)(qv >> 16));
    float s[16];
    const float* kb = ipk + (size_t)h * 16 * HD + d0;
    #pragma unroll
    for (int j = 0; j < 16; ++j) {
        float2 kk = *reinterpret_cast<const float2*>(kb + j * HD);
        float part = qx * kk.x + qy * kk.y;
        #pragma unroll
        for (int off = 1; off < 64; off <<= 1) part += __shfl_xor(part, off);
        s[j] = part * 0.08838834764831845f;
    }
    float mx = s[0];
    #pragma unroll
    for (int j = 1; j < 16; ++j) mx = fmaxf(mx, s[j]);
    float sum = 0.f;
    #pragma unroll
    for (int j = 0; j < 16; ++j) { s[j] = __expf(s[j] - mx); sum += s[j]; }
    float ox = 0.f, oy = 0.f;
    const float* vb = ipv + (size_t)h * 16 * HD + d0;
    #pragma unroll
    for (int j = 0; j < 16; ++j) {
        float2 vv = *reinterpret_cast<const float2*>(vb + j * HD);
        ox += s[j] * vv.x; oy += s[j] * vv.y;
    }
    float f = 0.6f * mask / sum;
    ax += f * ox; ay += f * oy;
    *reinterpret_cast<unsigned*>(concat + (size_t)l * K2 + h * HD + d0) =
        (unsigned)f2bf(ax) | ((unsigned)f2bf(ay) << 16);
}

extern "C" void kernel_launch(void* const* d_in, const int* in_sizes, int n_in,
                              void* d_out, int out_size, void* d_ws, size_t ws_size,
                              hipStream_t stream)
{
    (void)in_sizes; (void)n_in; (void)out_size; (void)ws_size;
    const float* x         = (const float*)d_in[0];
    const float* vec       = (const float*)d_in[1];
    const float* pe        = (const float*)d_in[2];
    const float* img_mask  = (const float*)d_in[3];
    const float* image_emb = (const float*)d_in[4];
    const float* mod_w     = (const float*)d_in[5];
    const float* mod_b     = (const float*)d_in[6];
    const float* lin1_w    = (const float*)d_in[7];
    const float* lin1_b    = (const float*)d_in[8];
    const float* q_scale   = (const float*)d_in[9];
    const float* k_scale   = (const float*)d_in[10];
    const float* lin2_w    = (const float*)d_in[11];
    const float* lin2_b    = (const float*)d_in[12];
    const float* ipk_w     = (const float*)d_in[13];
    const float* ipv_w     = (const float*)d_in[14];
    float* dout = (float*)d_out;

    char* wp = (char*)d_ws;
    auto alloc = [&](size_t bytes) { char* p = wp; wp += (bytes + 255) & ~(size_t)255; return p; };
    // persistent through GEMM2:
    float*    mod     = (float*)   alloc((size_t)9216 * 4);
    ushort_t* concat  = (ushort_t*)alloc((size_t)LSEQ * K2 * 2);
    ushort_t* lin2_bf = (ushort_t*)alloc((size_t)HID * K2 * 2);
    float*    ipk     = (float*)   alloc((size_t)NH * 16 * HD * 4);
    float*    ipv     = (float*)   alloc((size_t)NH * 16 * HD * 4);
    // union region: all dead before GEMM2; bf16 partial (4 * LSEQ * HID * 2B = 50.3 MB) aliases it
    char* ubase = wp;
    ushort_t* lin1_bf = (ushort_t*)alloc((size_t)N1 * HID * 2);     // 132.1 MB
    ushort_t* xmod    = (ushort_t*)alloc((size_t)LSEQ * HID * 2);
    ushort_t* qkv     = (ushort_t*)alloc((size_t)LSEQ * 3 * HID * 2);
    ushort_t* q_rope  = (ushort_t*)alloc((size_t)NH * LSEQ * HD * 2);
    ushort_t* k_rope  = (ushort_t*)alloc((size_t)NH * LSEQ * HD * 2);
    ushort_t* q_rms   = (ushort_t*)alloc((size_t)NH * LSEQ * HD * 2);
    ushort_t* v_t     = (ushort_t*)alloc((size_t)NH * HD * LSEQ * 2);
    ushort_t* partial = (ushort_t*)ubase;   // 50.3 MB <= union span

    hipFuncSetAttribute((const void*)k_gemm8, hipFuncAttributeMaxDynamicSharedMemorySize, 163840);
    hipFuncSetAttribute((const void*)k_gemm4, hipFuncAttributeMaxDynamicSharedMemorySize, 81920);

    k_cvt2  <<<dim3(4096), dim3(256), 0, stream>>>(lin1_w, lin1_bf, N1 * HID,
                                                   lin2_w, lin2_bf, HID * K2);
    k_mod   <<<dim3(9216 / 4), dim3(256), 0, stream>>>(vec, mod_w, mod_b, mod);
    k_lnmod <<<dim3(LSEQ), dim3(256), 0, stream>>>(x, mod, xmod);
    k_gemm8 <<<dim3(84, 8), dim3(512), 163840, stream>>>(xmod, lin1_bf, lin1_b, qkv, concat);
    k_qkv   <<<dim3(32, NH), dim3(256), 0, stream>>>(qkv, pe, q_scale, k_scale,
                                                     q_rope, k_rope, q_rms, v_t);
    k_ipgemv<<<dim3(2 * HID / 4), dim3(256), 0, stream>>>(image_emb, ipk_w, ipv_w, ipk, ipv);
    k_ipkrms<<<dim3(NH * 16 / 4), dim3(256), 0, stream>>>(ipk);
    k_attn  <<<dim3(32, NH), dim3(256), 0, stream>>>(q_rope, k_rope, v_t, concat);
    k_ipattn<<<dim3(NH * 1792 / 4), dim3(256), 0, stream>>>(q_rms, ipk, ipv, img_mask, concat);
    k_gemm4 <<<dim3(24, 16, 4), dim3(256), 81920, stream>>>(concat, lin2_bf, 3840, partial);
    k_red   <<<dim3(LSEQ * HID / 2048), dim3(256), 0, stream>>>(partial, lin2_b, x, mod, dout);
}